// Round 1
// baseline (1603.167 us; speedup 1.0000x reference)
//
#include <hip/hip_runtime.h>

// LiquidODECell: B=4096, D_IN=1024, H=2048, TAU_MIN=0.2, 3 RK2 steps.
// Strategy: f16 MFMA GEMMs (fp32 accum) with fused epilogues.
//   pre   = x@[W_ih;W_t1x]^T + biases          (once, K=1024, N=4096)
//   per dynamics eval:
//     GEMM_AB: h@[W_hh;W_t1h]^T  -> inter=tanh(..+ih_pre), t1=silu(..+t1x_pre) (f16)
//     GEMM_C : t1@W_t2^T         -> tau=softplus(..+b_t2)+0.2; RK2 combine fused
// 6 evals total. ~1.27 TFLOP, MFMA-bound.

typedef _Float16 f16;
typedef __attribute__((ext_vector_type(4))) _Float16 f16x4;
typedef __attribute__((ext_vector_type(8))) _Float16 f16x8;
typedef __attribute__((ext_vector_type(4))) float f32x4;

#define TAU_MIN_F 0.2f

// ---------------- async global->LDS (width 16) ----------------
__device__ __forceinline__ void glds16(const void* g, void* l) {
  __builtin_amdgcn_global_load_lds(
      (const __attribute__((address_space(1))) unsigned int*)g,
      (__attribute__((address_space(3))) unsigned int*)l,
      16, 0, 0);
}

// ---------------- prep kernels ----------------
__global__ void cvt4(const float* __restrict__ s, f16* __restrict__ d, int n4) {
  int i = blockIdx.x * 256 + threadIdx.x;
  if (i >= n4) return;
  float4 v = reinterpret_cast<const float4*>(s)[i];
  f16x4 o = {(_Float16)v.x, (_Float16)v.y, (_Float16)v.z, (_Float16)v.w};
  reinterpret_cast<f16x4*>(d)[i] = o;
}

// W_t1 is [2048, 3072]; cols 0..1023 -> Wpre rows 2048.., cols 1024..3071 -> Wab rows 2048..
__global__ void split_wt1(const float* __restrict__ Wt1, f16* __restrict__ Wpre,
                          f16* __restrict__ Wab) {
  int i = blockIdx.x * 256 + threadIdx.x;  // over 2048*768 float4 groups
  if (i >= 2048 * 768) return;
  int r = i / 768;
  int c4 = (i - r * 768) * 4;
  float4 v = reinterpret_cast<const float4*>(Wt1)[i];
  f16x4 o = {(_Float16)v.x, (_Float16)v.y, (_Float16)v.z, (_Float16)v.w};
  if (c4 < 1024)
    *reinterpret_cast<f16x4*>(Wpre + (size_t)(2048 + r) * 1024 + c4) = o;
  else
    *reinterpret_cast<f16x4*>(Wab + (size_t)(2048 + r) * 2048 + (c4 - 1024)) = o;
}

__global__ void biasprep(const float* __restrict__ bih, const float* __restrict__ bhh,
                         const float* __restrict__ bt1, float* __restrict__ biasp) {
  int i = blockIdx.x * 256 + threadIdx.x;
  if (i >= 4096) return;
  biasp[i] = (i < 2048) ? (bih[i] + bhh[i]) : bt1[i - 2048];
}

__global__ void init_h(const float* __restrict__ h, f16* __restrict__ hb,
                       float* __restrict__ hout) {
  int i = blockIdx.x * 256 + threadIdx.x;  // 4096*2048/4 groups
  if (i >= 4096 * 2048 / 4) return;
  float4 v = reinterpret_cast<const float4*>(h)[i];
  reinterpret_cast<float4*>(hout)[i] = v;
  f16x4 o = {(_Float16)v.x, (_Float16)v.y, (_Float16)v.z, (_Float16)v.w};
  reinterpret_cast<f16x4*>(hb)[i] = o;
}

// ---------------- GEMM with fused epilogues ----------------
// out[m][n] = sum_k A[m][k] * Bw[n][k]   (A:[M,K] f16 row-major, Bw:[N,K] f16 row-major)
struct EpArgs {
  const float* pre;   // EP0: bias_pre[N]; EP1: pre[M*4096]
  float* out_f;       // EP0: pre; EP1: inter; EP2: h_out (f32)
  f16* out_h;         // EP1: t1 f16; EP2: h_out f16
  const float* bt2;   // EP2
  const float* inter; // EP2
  const float* h_in;  // EP2  (the h the dynamics is evaluated at)
  const float* h_base;// EP2  (the h the RK2 update adds onto)
  float coef;         // EP2  (0.5*dt or dt)
};

template <int EP>
__global__ __launch_bounds__(256)
void gemm_bt(const f16* __restrict__ A, const f16* __restrict__ Bw,
             int M, int N, int K, EpArgs ep) {
  __shared__ __align__(16) f16 As[128 * 32];  // 8 KB
  __shared__ __align__(16) f16 Bs[128 * 32];  // 8 KB

  const int bm = blockIdx.x * 128;
  const int bn = blockIdx.y * 128;
  const int tid = threadIdx.x;
  const int lane = tid & 63;
  const int wid = tid >> 6;
  const int wm = (wid >> 1) * 64;
  const int wn = (wid & 1) * 64;

  // -------- staging addresses: 8KB tile = 4 waves x 2 instrs x 1KB --------
  const int off0 = wid * 2048 + lane * 16;  // byte offset within tile
  const int off1 = off0 + 1024;
  const int row0 = off0 >> 6, cb0 = off0 & 63;  // 64 B per row (BK=32 f16)
  const int row1 = off1 >> 6, cb1 = off1 & 63;
  const char* Ag0 = (const char*)(A + (size_t)(bm + row0) * K) + cb0;
  const char* Ag1 = (const char*)(A + (size_t)(bm + row1) * K) + cb1;
  const char* Bg0 = (const char*)(Bw + (size_t)(bn + row0) * K) + cb0;
  const char* Bg1 = (const char*)(Bw + (size_t)(bn + row1) * K) + cb1;
  char* Asb = (char*)As;
  char* Bsb = (char*)Bs;
  char* ldsA0 = Asb + wid * 2048;          // wave-uniform base; HW adds lane*16
  char* ldsA1 = Asb + wid * 2048 + 1024;
  char* ldsB0 = Bsb + wid * 2048;
  char* ldsB1 = Bsb + wid * 2048 + 1024;

  // -------- fragment read offsets (16x16x32: row=lane&15, kgrp=lane>>4) --------
  const int fr = lane & 15;
  const int kb = (lane >> 4) * 16;  // byte offset of 8-f16 k-group
  int aoff[4], boff[4];
#pragma unroll
  for (int i = 0; i < 4; ++i) {
    aoff[i] = (wm + i * 16 + fr) * 64 + kb;
    boff[i] = (wn + i * 16 + fr) * 64 + kb;
  }

  f32x4 acc[4][4] = {};

  const int nk = K >> 5;
  for (int kt = 0; kt < nk; ++kt) {
    const size_t kby = (size_t)kt * 64;
    glds16(Ag0 + kby, ldsA0);
    glds16(Ag1 + kby, ldsA1);
    glds16(Bg0 + kby, ldsB0);
    glds16(Bg1 + kby, ldsB1);
    __syncthreads();  // compiler emits vmcnt(0) drain before barrier

    f16x8 af[4], bf[4];
#pragma unroll
    for (int i = 0; i < 4; ++i) af[i] = *reinterpret_cast<const f16x8*>(Asb + aoff[i]);
#pragma unroll
    for (int i = 0; i < 4; ++i) bf[i] = *reinterpret_cast<const f16x8*>(Bsb + boff[i]);

#pragma unroll
    for (int mi = 0; mi < 4; ++mi)
#pragma unroll
      for (int ni = 0; ni < 4; ++ni)
        acc[mi][ni] =
            __builtin_amdgcn_mfma_f32_16x16x32_f16(af[mi], bf[ni], acc[mi][ni], 0, 0, 0);

    __syncthreads();  // protect LDS before next stage
  }

  // -------- epilogue: C/D map col=lane&15, row=(lane>>4)*4+j --------
  const int er = (lane >> 4) * 4;
  const int ec = lane & 15;
#pragma unroll
  for (int mi = 0; mi < 4; ++mi) {
#pragma unroll
    for (int ni = 0; ni < 4; ++ni) {
#pragma unroll
      for (int j = 0; j < 4; ++j) {
        const int gm = bm + wm + mi * 16 + er + j;
        const int gn = bn + wn + ni * 16 + ec;
        float v = acc[mi][ni][j];
        if constexpr (EP == 0) {
          // precompute: pre[m][n] = acc + bias_pre[n]
          ep.out_f[(size_t)gm * N + gn] = v + ep.pre[gn];
        } else if constexpr (EP == 1) {
          // AB: n<2048 -> interaction = tanh(acc + ih_pre); else t1 = silu(acc + t1x_pre)
          float u = v + ep.pre[(size_t)gm * 4096 + gn];
          if (gn < 2048) {
            ep.out_f[(size_t)gm * 2048 + gn] = tanhf(u);
          } else {
            float s = u / (1.0f + __expf(-u));
            ep.out_h[(size_t)gm * 2048 + (gn - 2048)] = (f16)s;
          }
        } else {
          // C: tau = softplus(acc + b_t2) + TAU_MIN ; RK2 combine
          float u = v + ep.bt2[gn];
          float sp = fmaxf(u, 0.0f) + log1pf(__expf(-fabsf(u)));
          float tau = sp + TAU_MIN_F;
          const size_t idx = (size_t)gm * 2048 + gn;
          float dh = (ep.inter[idx] - ep.h_in[idx]) / tau;
          float hn = ep.h_base[idx] + ep.coef * dh;
          ep.out_f[idx] = hn;
          ep.out_h[idx] = (f16)hn;
        }
      }
    }
  }
}

// ---------------- launch ----------------
extern "C" void kernel_launch(void* const* d_in, const int* in_sizes, int n_in,
                              void* d_out, int out_size, void* d_ws, size_t ws_size,
                              hipStream_t stream) {
  const float* x   = (const float*)d_in[0];
  const float* h   = (const float*)d_in[1];
  const float* Wih = (const float*)d_in[2];
  const float* bih = (const float*)d_in[3];
  const float* Whh = (const float*)d_in[4];
  const float* bhh = (const float*)d_in[5];
  const float* Wt1 = (const float*)d_in[6];
  const float* bt1 = (const float*)d_in[7];
  const float* Wt2 = (const float*)d_in[8];
  const float* bt2 = (const float*)d_in[9];
  float* hout = (float*)d_out;

  char* p = (char*)d_ws;
  auto alloc = [&](size_t bytes) {
    char* r = p;
    p += (bytes + 255) & ~(size_t)255;
    return r;
  };
  f16* xb    = (f16*)alloc((size_t)4096 * 1024 * 2);
  f16* Wpre  = (f16*)alloc((size_t)4096 * 1024 * 2);   // [W_ih; W_t1x] as [4096,1024]
  f16* Wab   = (f16*)alloc((size_t)4096 * 2048 * 2);   // [W_hh; W_t1h] as [4096,2048]
  f16* Wt2b  = (f16*)alloc((size_t)2048 * 2048 * 2);
  f16* hb    = (f16*)alloc((size_t)4096 * 2048 * 2);
  f16* hmb   = (f16*)alloc((size_t)4096 * 2048 * 2);
  f16* t1b   = (f16*)alloc((size_t)4096 * 2048 * 2);
  float* pre   = (float*)alloc((size_t)4096 * 4096 * 4);  // [ih+b_ih+b_hh | t1x+b_t1]
  float* inter = (float*)alloc((size_t)4096 * 2048 * 4);
  float* hmid  = (float*)alloc((size_t)4096 * 2048 * 4);
  float* biasp = (float*)alloc(4096 * 4);

  // prep: converts / packs / h init
  cvt4<<<(4096 * 1024 / 4 + 255) / 256, 256, 0, stream>>>(x, xb, 4096 * 1024 / 4);
  cvt4<<<(2048 * 1024 / 4 + 255) / 256, 256, 0, stream>>>(Wih, Wpre, 2048 * 1024 / 4);
  cvt4<<<(2048 * 2048 / 4 + 255) / 256, 256, 0, stream>>>(Whh, Wab, 2048 * 2048 / 4);
  cvt4<<<(2048 * 2048 / 4 + 255) / 256, 256, 0, stream>>>(Wt2, Wt2b, 2048 * 2048 / 4);
  split_wt1<<<(2048 * 768 + 255) / 256, 256, 0, stream>>>(Wt1, Wpre, Wab);
  biasprep<<<16, 256, 0, stream>>>(bih, bhh, bt1, biasp);
  init_h<<<(4096 * 2048 / 4) / 256, 256, 0, stream>>>(h, hb, hout);

  // precompute pre = x @ [W_ih;W_t1x]^T + bias_pre   (M=4096, N=4096, K=1024)
  {
    EpArgs e{};
    e.pre = biasp;
    e.out_f = pre;
    gemm_bt<0><<<dim3(32, 32), 256, 0, stream>>>(xb, Wpre, 4096, 4096, 1024, e);
  }

  const float dt = 1.0f / 3.0f;
  for (int s = 0; s < 3; ++s) {
    // k1 at h: AB then C (h_mid = h + 0.5*dt*k1)
    {
      EpArgs e{};
      e.pre = pre; e.out_f = inter; e.out_h = t1b;
      gemm_bt<1><<<dim3(32, 32), 256, 0, stream>>>(hb, Wab, 4096, 4096, 2048, e);
    }
    {
      EpArgs e{};
      e.bt2 = bt2; e.inter = inter; e.h_in = hout; e.h_base = hout;
      e.coef = 0.5f * dt; e.out_f = hmid; e.out_h = hmb;
      gemm_bt<2><<<dim3(32, 16), 256, 0, stream>>>(t1b, Wt2b, 4096, 2048, 2048, e);
    }
    // k2 at h_mid: AB then C (h = h + dt*k2)
    {
      EpArgs e{};
      e.pre = pre; e.out_f = inter; e.out_h = t1b;
      gemm_bt<1><<<dim3(32, 32), 256, 0, stream>>>(hmb, Wab, 4096, 4096, 2048, e);
    }
    {
      EpArgs e{};
      e.bt2 = bt2; e.inter = inter; e.h_in = hmid; e.h_base = hout;
      e.coef = dt; e.out_f = hout; e.out_h = hb;
      gemm_bt<2><<<dim3(32, 16), 256, 0, stream>>>(t1b, Wt2b, 4096, 2048, 2048, e);
    }
  }
}

// Round 2
// 1526.665 us; speedup vs baseline: 1.0501x; 1.0501x over previous
//
#include <hip/hip_runtime.h>

// LiquidODECell: B=4096, D_IN=1024, H=2048, TAU_MIN=0.2, 3 RK2 steps.
// f16 MFMA GEMMs (fp32 accum) with fused epilogues, minimized inter-kernel traffic:
//   pre16 = f16(x@[W_ih;W_t1x]^T + biases)                (once, K=1024, N=4096)
//   per dynamics eval:
//     EP1: h@[W_hh;W_t1h]^T -> diff=f16(tanh(..+ihpre)-h), t1=f16(silu(..+t1xpre))
//     EP2: t1@W_t2^T        -> tau=softplus(..+b_t2)+0.2; h' = h_base + coef*diff/tau
// All ODE-loop tensors f16 except the fp32 h accumulator (hout).

typedef _Float16 f16;
typedef __attribute__((ext_vector_type(4))) _Float16 f16x4;
typedef __attribute__((ext_vector_type(8))) _Float16 f16x8;
typedef __attribute__((ext_vector_type(4))) float f32x4;

#define TAU_MIN_F 0.2f

__device__ __forceinline__ float rcp_fast(float x) { return __builtin_amdgcn_rcpf(x); }
__device__ __forceinline__ float tanh_fast(float u) {
  float t = __expf(2.0f * u);            // 0..inf
  return 1.0f - 2.0f * rcp_fast(t + 1.0f);
}
__device__ __forceinline__ float silu_fast(float u) {
  return u * rcp_fast(1.0f + __expf(-u));
}
__device__ __forceinline__ float softplus_fast(float u) {
  return fmaxf(u, 0.0f) + __logf(1.0f + __expf(-fabsf(u)));
}

// ---------------- async global->LDS (width 16) ----------------
__device__ __forceinline__ void glds16(const void* g, void* l) {
  __builtin_amdgcn_global_load_lds(
      (const __attribute__((address_space(1))) unsigned int*)g,
      (__attribute__((address_space(3))) unsigned int*)l,
      16, 0, 0);
}

// ---------------- prep kernels ----------------
__global__ void cvt4(const float* __restrict__ s, f16* __restrict__ d, int n4) {
  int i = blockIdx.x * 256 + threadIdx.x;
  if (i >= n4) return;
  float4 v = reinterpret_cast<const float4*>(s)[i];
  f16x4 o = {(_Float16)v.x, (_Float16)v.y, (_Float16)v.z, (_Float16)v.w};
  reinterpret_cast<f16x4*>(d)[i] = o;
}

// W_t1 is [2048, 3072]; cols 0..1023 -> Wpre rows 2048.., cols 1024..3071 -> Wab rows 2048..
__global__ void split_wt1(const float* __restrict__ Wt1, f16* __restrict__ Wpre,
                          f16* __restrict__ Wab) {
  int i = blockIdx.x * 256 + threadIdx.x;  // over 2048*768 float4 groups
  if (i >= 2048 * 768) return;
  int r = i / 768;
  int c4 = (i - r * 768) * 4;
  float4 v = reinterpret_cast<const float4*>(Wt1)[i];
  f16x4 o = {(_Float16)v.x, (_Float16)v.y, (_Float16)v.z, (_Float16)v.w};
  if (c4 < 1024)
    *reinterpret_cast<f16x4*>(Wpre + (size_t)(2048 + r) * 1024 + c4) = o;
  else
    *reinterpret_cast<f16x4*>(Wab + (size_t)(2048 + r) * 2048 + (c4 - 1024)) = o;
}

__global__ void biasprep(const float* __restrict__ bih, const float* __restrict__ bhh,
                         const float* __restrict__ bt1, float* __restrict__ biasp) {
  int i = blockIdx.x * 256 + threadIdx.x;
  if (i >= 4096) return;
  biasp[i] = (i < 2048) ? (bih[i] + bhh[i]) : bt1[i - 2048];
}

__global__ void init_h(const float* __restrict__ h, f16* __restrict__ hb,
                       float* __restrict__ hout) {
  int i = blockIdx.x * 256 + threadIdx.x;  // 4096*2048/4 groups
  if (i >= 4096 * 2048 / 4) return;
  float4 v = reinterpret_cast<const float4*>(h)[i];
  reinterpret_cast<float4*>(hout)[i] = v;
  f16x4 o = {(_Float16)v.x, (_Float16)v.y, (_Float16)v.z, (_Float16)v.w};
  reinterpret_cast<f16x4*>(hb)[i] = o;
}

// ---------------- GEMM with fused epilogues ----------------
// out[m][n] = sum_k A[m][k] * Bw[n][k]   (A:[M,K] f16 row-major, Bw:[N,K] f16 row-major)
struct EpArgs {
  const float* biasf;   // EP0: bias_pre[N]
  const f16* pre16;     // EP1: pre [M,4096] f16
  const f16* h16;       // EP1: the h this dynamics is evaluated at (f16, = A ptr)
  f16* out_d;           // EP1: diff f16
  f16* out_h;           // EP0: pre16 out; EP1: t1 f16; EP2: h' f16
  const float* bt2;     // EP2
  const f16* diff;      // EP2
  const float* h_base;  // EP2 (fp32 accumulator input)
  float* out_f;         // EP2: fp32 h' out (nullable)
  float coef;           // EP2 (0.5*dt or dt)
};

template <int EP>
__global__ __launch_bounds__(256)
void gemm_bt(const f16* __restrict__ A, const f16* __restrict__ Bw,
             int M, int N, int K, EpArgs ep) {
  __shared__ __align__(16) f16 As[128 * 32];  // 8 KB
  __shared__ __align__(16) f16 Bs[128 * 32];  // 8 KB

  // T1: XCD-aware block swizzle (nwg % 8 == 0 for all our grids)
  const int gx = gridDim.x;
  const int nwg = gx * gridDim.y;
  const int orig = blockIdx.y * gx + blockIdx.x;
  const int cpx = nwg >> 3;
  const int w = (orig & 7) * cpx + (orig >> 3);
  const int bm = (w % gx) * 128;
  const int bn = (w / gx) * 128;

  const int tid = threadIdx.x;
  const int lane = tid & 63;
  const int wid = tid >> 6;
  const int wm = (wid >> 1) * 64;
  const int wn = (wid & 1) * 64;

  // -------- staging addresses: 8KB tile = 4 waves x 2 instrs x 1KB --------
  const int off0 = wid * 2048 + lane * 16;  // byte offset within tile
  const int off1 = off0 + 1024;
  const int row0 = off0 >> 6, cb0 = off0 & 63;  // 64 B per row (BK=32 f16)
  const int row1 = off1 >> 6, cb1 = off1 & 63;
  const char* Ag0 = (const char*)(A + (size_t)(bm + row0) * K) + cb0;
  const char* Ag1 = (const char*)(A + (size_t)(bm + row1) * K) + cb1;
  const char* Bg0 = (const char*)(Bw + (size_t)(bn + row0) * K) + cb0;
  const char* Bg1 = (const char*)(Bw + (size_t)(bn + row1) * K) + cb1;
  char* Asb = (char*)As;
  char* Bsb = (char*)Bs;
  char* ldsA0 = Asb + wid * 2048;          // wave-uniform base; HW adds lane*16
  char* ldsA1 = Asb + wid * 2048 + 1024;
  char* ldsB0 = Bsb + wid * 2048;
  char* ldsB1 = Bsb + wid * 2048 + 1024;

  // -------- fragment read offsets (16x16x32: row=lane&15, kgrp=lane>>4) --------
  const int fr = lane & 15;
  const int kb = (lane >> 4) * 16;  // byte offset of 8-f16 k-group
  int aoff[4], boff[4];
#pragma unroll
  for (int i = 0; i < 4; ++i) {
    aoff[i] = (wm + i * 16 + fr) * 64 + kb;
    boff[i] = (wn + i * 16 + fr) * 64 + kb;
  }

  f32x4 acc[4][4] = {};

  const int nk = K >> 5;
  for (int kt = 0; kt < nk; ++kt) {
    const size_t kby = (size_t)kt * 64;
    glds16(Ag0 + kby, ldsA0);
    glds16(Ag1 + kby, ldsA1);
    glds16(Bg0 + kby, ldsB0);
    glds16(Bg1 + kby, ldsB1);
    __syncthreads();

    f16x8 af[4], bf[4];
#pragma unroll
    for (int i = 0; i < 4; ++i) af[i] = *reinterpret_cast<const f16x8*>(Asb + aoff[i]);
#pragma unroll
    for (int i = 0; i < 4; ++i) bf[i] = *reinterpret_cast<const f16x8*>(Bsb + boff[i]);

#pragma unroll
    for (int mi = 0; mi < 4; ++mi)
#pragma unroll
      for (int ni = 0; ni < 4; ++ni)
        acc[mi][ni] =
            __builtin_amdgcn_mfma_f32_16x16x32_f16(af[mi], bf[ni], acc[mi][ni], 0, 0, 0);

    __syncthreads();
  }

  // -------- epilogue: C/D map col=lane&15, row=(lane>>4)*4+j --------
  const int er = (lane >> 4) * 4;
  const int ec = lane & 15;
#pragma unroll
  for (int mi = 0; mi < 4; ++mi) {
#pragma unroll
    for (int ni = 0; ni < 4; ++ni) {
#pragma unroll
      for (int j = 0; j < 4; ++j) {
        const int gm = bm + wm + mi * 16 + er + j;
        const int gn = bn + wn + ni * 16 + ec;
        float v = acc[mi][ni][j];
        if constexpr (EP == 0) {
          // precompute: pre[m][n] = f16(acc + bias_pre[n])
          ep.out_h[(size_t)gm * N + gn] = (f16)(v + ep.biasf[gn]);
        } else if constexpr (EP == 1) {
          // AB: n<2048 -> diff = tanh(acc+ih_pre) - h ; else t1 = silu(acc+t1x_pre)
          float u = v + (float)ep.pre16[(size_t)gm * 4096 + gn];
          if (gn < 2048) {
            float d = tanh_fast(u) - (float)ep.h16[(size_t)gm * 2048 + gn];
            ep.out_d[(size_t)gm * 2048 + gn] = (f16)d;
          } else {
            ep.out_h[(size_t)gm * 2048 + (gn - 2048)] = (f16)silu_fast(u);
          }
        } else {
          // C: tau = softplus(acc + b_t2) + TAU_MIN ; RK2 combine
          float u = v + ep.bt2[gn];
          float tau = softplus_fast(u) + TAU_MIN_F;
          const size_t idx = (size_t)gm * 2048 + gn;
          float dh = (float)ep.diff[idx] * rcp_fast(tau);
          float hn = ep.h_base[idx] + ep.coef * dh;
          if (ep.out_f) ep.out_f[idx] = hn;
          ep.out_h[idx] = (f16)hn;
        }
      }
    }
  }
}

// ---------------- launch ----------------
extern "C" void kernel_launch(void* const* d_in, const int* in_sizes, int n_in,
                              void* d_out, int out_size, void* d_ws, size_t ws_size,
                              hipStream_t stream) {
  const float* x   = (const float*)d_in[0];
  const float* h   = (const float*)d_in[1];
  const float* Wih = (const float*)d_in[2];
  const float* bih = (const float*)d_in[3];
  const float* Whh = (const float*)d_in[4];
  const float* bhh = (const float*)d_in[5];
  const float* Wt1 = (const float*)d_in[6];
  const float* bt1 = (const float*)d_in[7];
  const float* Wt2 = (const float*)d_in[8];
  const float* bt2 = (const float*)d_in[9];
  float* hout = (float*)d_out;

  char* p = (char*)d_ws;
  auto alloc = [&](size_t bytes) {
    char* r = p;
    p += (bytes + 255) & ~(size_t)255;
    return r;
  };
  f16* xb    = (f16*)alloc((size_t)4096 * 1024 * 2);
  f16* Wpre  = (f16*)alloc((size_t)4096 * 1024 * 2);   // [W_ih; W_t1x] as [4096,1024]
  f16* Wab   = (f16*)alloc((size_t)4096 * 2048 * 2);   // [W_hh; W_t1h] as [4096,2048]
  f16* Wt2b  = (f16*)alloc((size_t)2048 * 2048 * 2);
  f16* hb    = (f16*)alloc((size_t)4096 * 2048 * 2);
  f16* hmb   = (f16*)alloc((size_t)4096 * 2048 * 2);
  f16* t1b   = (f16*)alloc((size_t)4096 * 2048 * 2);
  f16* pre16 = (f16*)alloc((size_t)4096 * 4096 * 2);   // [ih+b_ih+b_hh | t1x+b_t1] f16
  f16* dif16 = (f16*)alloc((size_t)4096 * 2048 * 2);
  float* biasp = (float*)alloc(4096 * 4);

  // prep: converts / packs / h init
  cvt4<<<(4096 * 1024 / 4 + 255) / 256, 256, 0, stream>>>(x, xb, 4096 * 1024 / 4);
  cvt4<<<(2048 * 1024 / 4 + 255) / 256, 256, 0, stream>>>(Wih, Wpre, 2048 * 1024 / 4);
  cvt4<<<(2048 * 2048 / 4 + 255) / 256, 256, 0, stream>>>(Whh, Wab, 2048 * 2048 / 4);
  cvt4<<<(2048 * 2048 / 4 + 255) / 256, 256, 0, stream>>>(Wt2, Wt2b, 2048 * 2048 / 4);
  split_wt1<<<(2048 * 768 + 255) / 256, 256, 0, stream>>>(Wt1, Wpre, Wab);
  biasprep<<<16, 256, 0, stream>>>(bih, bhh, bt1, biasp);
  init_h<<<(4096 * 2048 / 4) / 256, 256, 0, stream>>>(h, hb, hout);

  // precompute pre16 = f16(x @ [W_ih;W_t1x]^T + bias_pre)   (M=4096, N=4096, K=1024)
  {
    EpArgs e{};
    e.biasf = biasp;
    e.out_h = pre16;
    gemm_bt<0><<<dim3(32, 32), 256, 0, stream>>>(xb, Wpre, 4096, 4096, 1024, e);
  }

  const float dt = 1.0f / 3.0f;
  for (int s = 0; s < 3; ++s) {
    // k1 at h: EP1 then EP2 (h_mid = h + 0.5*dt*k1, f16 only)
    {
      EpArgs e{};
      e.pre16 = pre16; e.h16 = hb; e.out_d = dif16; e.out_h = t1b;
      gemm_bt<1><<<dim3(32, 32), 256, 0, stream>>>(hb, Wab, 4096, 4096, 2048, e);
    }
    {
      EpArgs e{};
      e.bt2 = bt2; e.diff = dif16; e.h_base = hout;
      e.coef = 0.5f * dt; e.out_f = nullptr; e.out_h = hmb;
      gemm_bt<2><<<dim3(32, 16), 256, 0, stream>>>(t1b, Wt2b, 4096, 2048, 2048, e);
    }
    // k2 at h_mid: EP1 then EP2 (h = h + dt*k2, fp32 + f16)
    {
      EpArgs e{};
      e.pre16 = pre16; e.h16 = hmb; e.out_d = dif16; e.out_h = t1b;
      gemm_bt<1><<<dim3(32, 32), 256, 0, stream>>>(hmb, Wab, 4096, 4096, 2048, e);
    }
    {
      EpArgs e{};
      e.bt2 = bt2; e.diff = dif16; e.h_base = hout;
      e.coef = dt; e.out_f = hout; e.out_h = hb;
      gemm_bt<2><<<dim3(32, 16), 256, 0, stream>>>(t1b, Wt2b, 4096, 2048, 2048, e);
    }
  }
}

// Round 3
// 1225.526 us; speedup vs baseline: 1.3081x; 1.2457x over previous
//
#include <hip/hip_runtime.h>

// LiquidODECell: B=4096, D_IN=1024, H=2048, TAU_MIN=0.2, 3 RK2 steps.
// f16 MFMA GEMMs (fp32 accum) with fused, LDS-transposed (fully coalesced) epilogues:
//   pre16 = f16(x@[W_ih;W_t1x]^T + biases)                (once, K=1024, N=4096)
//   per dynamics eval:
//     EP1: h@[W_hh;W_t1h]^T -> diff=f16(tanh(..+ihpre)-h), t1=f16(silu(..+t1xpre))
//     EP2: t1@W_t2^T        -> tau=softplus(..+b_t2)+0.2; h' = h_base + coef*diff/tau

typedef _Float16 f16;
typedef __attribute__((ext_vector_type(4))) _Float16 f16x4;
typedef __attribute__((ext_vector_type(8))) _Float16 f16x8;
typedef __attribute__((ext_vector_type(4))) float f32x4;

#define TAU_MIN_F 0.2f

__device__ __forceinline__ float rcp_fast(float x) { return __builtin_amdgcn_rcpf(x); }
__device__ __forceinline__ float tanh_fast(float u) {
  float t = __expf(2.0f * u);
  return 1.0f - 2.0f * rcp_fast(t + 1.0f);
}
__device__ __forceinline__ float silu_fast(float u) {
  return u * rcp_fast(1.0f + __expf(-u));
}
__device__ __forceinline__ float softplus_fast(float u) {
  return fmaxf(u, 0.0f) + __logf(1.0f + __expf(-fabsf(u)));
}

// ---------------- async global->LDS (width 16) ----------------
__device__ __forceinline__ void glds16(const void* g, void* l) {
  __builtin_amdgcn_global_load_lds(
      (const __attribute__((address_space(1))) unsigned int*)g,
      (__attribute__((address_space(3))) unsigned int*)l,
      16, 0, 0);
}

// ---------------- prep kernels ----------------
__global__ void cvt4(const float* __restrict__ s, f16* __restrict__ d, int n4) {
  int i = blockIdx.x * 256 + threadIdx.x;
  if (i >= n4) return;
  float4 v = reinterpret_cast<const float4*>(s)[i];
  f16x4 o = {(_Float16)v.x, (_Float16)v.y, (_Float16)v.z, (_Float16)v.w};
  reinterpret_cast<f16x4*>(d)[i] = o;
}

// W_t1 is [2048, 3072]; cols 0..1023 -> Wpre rows 2048.., cols 1024..3071 -> Wab rows 2048..
__global__ void split_wt1(const float* __restrict__ Wt1, f16* __restrict__ Wpre,
                          f16* __restrict__ Wab) {
  int i = blockIdx.x * 256 + threadIdx.x;  // over 2048*768 float4 groups
  if (i >= 2048 * 768) return;
  int r = i / 768;
  int c4 = (i - r * 768) * 4;
  float4 v = reinterpret_cast<const float4*>(Wt1)[i];
  f16x4 o = {(_Float16)v.x, (_Float16)v.y, (_Float16)v.z, (_Float16)v.w};
  if (c4 < 1024)
    *reinterpret_cast<f16x4*>(Wpre + (size_t)(2048 + r) * 1024 + c4) = o;
  else
    *reinterpret_cast<f16x4*>(Wab + (size_t)(2048 + r) * 2048 + (c4 - 1024)) = o;
}

__global__ void biasprep(const float* __restrict__ bih, const float* __restrict__ bhh,
                         const float* __restrict__ bt1, float* __restrict__ biasp) {
  int i = blockIdx.x * 256 + threadIdx.x;
  if (i >= 4096) return;
  biasp[i] = (i < 2048) ? (bih[i] + bhh[i]) : bt1[i - 2048];
}

__global__ void init_h(const float* __restrict__ h, f16* __restrict__ hb,
                       float* __restrict__ hout) {
  int i = blockIdx.x * 256 + threadIdx.x;  // 4096*2048/4 groups
  if (i >= 4096 * 2048 / 4) return;
  float4 v = reinterpret_cast<const float4*>(h)[i];
  reinterpret_cast<float4*>(hout)[i] = v;
  f16x4 o = {(_Float16)v.x, (_Float16)v.y, (_Float16)v.z, (_Float16)v.w};
  reinterpret_cast<f16x4*>(hb)[i] = o;
}

// ---------------- GEMM with fused epilogues ----------------
// out[m][n] = sum_k A[m][k] * Bw[n][k]   (A:[M,K] f16 row-major, Bw:[N,K] f16 row-major)
struct EpArgs {
  const float* biasf;   // EP0: bias_pre[N]
  const f16* pre16;     // EP1: pre [M,4096] f16
  const f16* h16;       // EP1: the h this dynamics is evaluated at (f16)
  f16* out_d;           // EP1: diff f16
  f16* out_h;           // EP0: pre16 out; EP1: t1 f16; EP2: h' f16
  const float* bt2;     // EP2
  const f16* diff;      // EP2
  const float* h_base;  // EP2 (fp32 accumulator input)
  float* out_f;         // EP2: fp32 h' out (nullable)
  float coef;           // EP2 (0.5*dt or dt)
};

template <int EP>
__global__ __launch_bounds__(256)
void gemm_bt(const f16* __restrict__ A, const f16* __restrict__ Bw,
             int M, int N, int K, EpArgs ep) {
  __shared__ __align__(16) f16 SH[8192];  // 16 KB: As(8K) | Bs(8K); reused by epilogue

  // T1: XCD-aware block swizzle (nwg % 8 == 0 for all our grids)
  const int gx = gridDim.x;
  const int nwg = gx * gridDim.y;
  const int orig = blockIdx.y * gx + blockIdx.x;
  const int cpx = nwg >> 3;
  const int w = (orig & 7) * cpx + (orig >> 3);
  const int bm = (w % gx) * 128;
  const int bn = (w / gx) * 128;

  const int tid = threadIdx.x;
  const int lane = tid & 63;
  const int wid = tid >> 6;
  const int wm = (wid >> 1) * 64;
  const int wn = (wid & 1) * 64;

  char* Asb = (char*)SH;
  char* Bsb = (char*)(SH + 4096);

  // -------- staging addresses: 8KB tile = 4 waves x 2 instrs x 1KB --------
  const int off0 = wid * 2048 + lane * 16;  // byte offset within tile
  const int off1 = off0 + 1024;
  const int row0 = off0 >> 6, cb0 = off0 & 63;  // 64 B per row (BK=32 f16)
  const int row1 = off1 >> 6, cb1 = off1 & 63;
  const char* Ag0 = (const char*)(A + (size_t)(bm + row0) * K) + cb0;
  const char* Ag1 = (const char*)(A + (size_t)(bm + row1) * K) + cb1;
  const char* Bg0 = (const char*)(Bw + (size_t)(bn + row0) * K) + cb0;
  const char* Bg1 = (const char*)(Bw + (size_t)(bn + row1) * K) + cb1;
  char* ldsA0 = Asb + wid * 2048;  // wave-uniform base; HW adds lane*16
  char* ldsA1 = Asb + wid * 2048 + 1024;
  char* ldsB0 = Bsb + wid * 2048;
  char* ldsB1 = Bsb + wid * 2048 + 1024;

  // -------- fragment read offsets (16x16x32: row=lane&15, kgrp=lane>>4) --------
  const int fr = lane & 15;
  const int kb = (lane >> 4) * 16;  // byte offset of 8-f16 k-group
  int aoff[4], boff[4];
#pragma unroll
  for (int i = 0; i < 4; ++i) {
    aoff[i] = (wm + i * 16 + fr) * 64 + kb;
    boff[i] = (wn + i * 16 + fr) * 64 + kb;
  }

  f32x4 acc[4][4] = {};

  const int nk = K >> 5;
  for (int kt = 0; kt < nk; ++kt) {
    const size_t kby = (size_t)kt * 64;
    glds16(Ag0 + kby, ldsA0);
    glds16(Ag1 + kby, ldsA1);
    glds16(Bg0 + kby, ldsB0);
    glds16(Bg1 + kby, ldsB1);
    __syncthreads();

    f16x8 af[4], bf[4];
#pragma unroll
    for (int i = 0; i < 4; ++i) af[i] = *reinterpret_cast<const f16x8*>(Asb + aoff[i]);
#pragma unroll
    for (int i = 0; i < 4; ++i) bf[i] = *reinterpret_cast<const f16x8*>(Bsb + boff[i]);

#pragma unroll
    for (int mi = 0; mi < 4; ++mi)
#pragma unroll
      for (int ni = 0; ni < 4; ++ni)
        acc[mi][ni] =
            __builtin_amdgcn_mfma_f32_16x16x32_f16(af[mi], bf[ni], acc[mi][ni], 0, 0, 0);

    __syncthreads();  // also guarantees LDS free for the epilogue transpose
  }

  // -------- epilogue via per-wave LDS transpose (full-line coalesced I/O) --------
  // C/D frag map: col=lane&15, row=(lane>>4)*4+j. Scatter 16 rows x 64 cols (f16,
  // stride 68 to spread banks), read back row-major f16x8 per lane.
  f16* tb = SH + wid * 1088;  // 16*68 f16 per wave, private region
  const int er = (lane >> 4) * 4;
  const int ec = lane & 15;
  const int rr = lane >> 3;        // 0..7
  const int cc = (lane & 7) * 8;   // 0..56
  const int colbase = bn + wn;     // uniform per wave

#pragma unroll
  for (int mi = 0; mi < 4; ++mi) {
#pragma unroll
    for (int ni = 0; ni < 4; ++ni)
#pragma unroll
      for (int j = 0; j < 4; ++j)
        tb[(er + j) * 68 + ni * 16 + ec] = (f16)acc[mi][ni][j];
    // same-wave DS ordering: reads below observe the writes above
#pragma unroll
    for (int it = 0; it < 2; ++it) {
      const int row = rr + it * 8;
      const int gm = bm + wm + mi * 16 + row;
      const int gn = colbase + cc;
      f16x8 v = *reinterpret_cast<const f16x8*>(tb + row * 68 + cc);
      if constexpr (EP == 0) {
        float4 b0 = *reinterpret_cast<const float4*>(ep.biasf + gn);
        float4 b1 = *reinterpret_cast<const float4*>(ep.biasf + gn + 4);
        f16x8 o;
        o[0] = (f16)((float)v[0] + b0.x); o[1] = (f16)((float)v[1] + b0.y);
        o[2] = (f16)((float)v[2] + b0.z); o[3] = (f16)((float)v[3] + b0.w);
        o[4] = (f16)((float)v[4] + b1.x); o[5] = (f16)((float)v[5] + b1.y);
        o[6] = (f16)((float)v[6] + b1.z); o[7] = (f16)((float)v[7] + b1.w);
        *reinterpret_cast<f16x8*>(ep.out_h + (size_t)gm * N + gn) = o;
      } else if constexpr (EP == 1) {
        f16x8 pr = *reinterpret_cast<const f16x8*>(ep.pre16 + (size_t)gm * 4096 + gn);
        if (colbase < 2048) {
          f16x8 hh = *reinterpret_cast<const f16x8*>(ep.h16 + (size_t)gm * 2048 + gn);
          f16x8 o;
#pragma unroll
          for (int k = 0; k < 8; ++k) {
            float u = (float)v[k] + (float)pr[k];
            o[k] = (f16)(tanh_fast(u) - (float)hh[k]);
          }
          *reinterpret_cast<f16x8*>(ep.out_d + (size_t)gm * 2048 + gn) = o;
        } else {
          f16x8 o;
#pragma unroll
          for (int k = 0; k < 8; ++k) {
            float u = (float)v[k] + (float)pr[k];
            o[k] = (f16)silu_fast(u);
          }
          *reinterpret_cast<f16x8*>(ep.out_h + (size_t)gm * 2048 + (gn - 2048)) = o;
        }
      } else {
        const size_t idx = (size_t)gm * 2048 + gn;
        float4 b0 = *reinterpret_cast<const float4*>(ep.bt2 + gn);
        float4 b1 = *reinterpret_cast<const float4*>(ep.bt2 + gn + 4);
        f16x8 df = *reinterpret_cast<const f16x8*>(ep.diff + idx);
        float4 h0 = *reinterpret_cast<const float4*>(ep.h_base + idx);
        float4 h1 = *reinterpret_cast<const float4*>(ep.h_base + idx + 4);
        float bb[8] = {b0.x, b0.y, b0.z, b0.w, b1.x, b1.y, b1.z, b1.w};
        float hb8[8] = {h0.x, h0.y, h0.z, h0.w, h1.x, h1.y, h1.z, h1.w};
        f16x8 o16;
        float on[8];
#pragma unroll
        for (int k = 0; k < 8; ++k) {
          float u = (float)v[k] + bb[k];
          float tau = softplus_fast(u) + TAU_MIN_F;
          float hn = hb8[k] + ep.coef * ((float)df[k] * rcp_fast(tau));
          on[k] = hn;
          o16[k] = (f16)hn;
        }
        *reinterpret_cast<f16x8*>(ep.out_h + idx) = o16;
        if (ep.out_f) {
          float4 o0 = {on[0], on[1], on[2], on[3]};
          float4 o1 = {on[4], on[5], on[6], on[7]};
          *reinterpret_cast<float4*>(ep.out_f + idx) = o0;
          *reinterpret_cast<float4*>(ep.out_f + idx + 4) = o1;
        }
      }
    }
  }
}

// ---------------- launch ----------------
extern "C" void kernel_launch(void* const* d_in, const int* in_sizes, int n_in,
                              void* d_out, int out_size, void* d_ws, size_t ws_size,
                              hipStream_t stream) {
  const float* x   = (const float*)d_in[0];
  const float* h   = (const float*)d_in[1];
  const float* Wih = (const float*)d_in[2];
  const float* bih = (const float*)d_in[3];
  const float* Whh = (const float*)d_in[4];
  const float* bhh = (const float*)d_in[5];
  const float* Wt1 = (const float*)d_in[6];
  const float* bt1 = (const float*)d_in[7];
  const float* Wt2 = (const float*)d_in[8];
  const float* bt2 = (const float*)d_in[9];
  float* hout = (float*)d_out;

  char* p = (char*)d_ws;
  auto alloc = [&](size_t bytes) {
    char* r = p;
    p += (bytes + 255) & ~(size_t)255;
    return r;
  };
  f16* xb    = (f16*)alloc((size_t)4096 * 1024 * 2);
  f16* Wpre  = (f16*)alloc((size_t)4096 * 1024 * 2);   // [W_ih; W_t1x] as [4096,1024]
  f16* Wab   = (f16*)alloc((size_t)4096 * 2048 * 2);   // [W_hh; W_t1h] as [4096,2048]
  f16* Wt2b  = (f16*)alloc((size_t)2048 * 2048 * 2);
  f16* hb    = (f16*)alloc((size_t)4096 * 2048 * 2);
  f16* hmb   = (f16*)alloc((size_t)4096 * 2048 * 2);
  f16* t1b   = (f16*)alloc((size_t)4096 * 2048 * 2);
  f16* pre16 = (f16*)alloc((size_t)4096 * 4096 * 2);   // [ih+b_ih+b_hh | t1x+b_t1] f16
  f16* dif16 = (f16*)alloc((size_t)4096 * 2048 * 2);
  float* biasp = (float*)alloc(4096 * 4);

  // prep: converts / packs / h init
  cvt4<<<(4096 * 1024 / 4 + 255) / 256, 256, 0, stream>>>(x, xb, 4096 * 1024 / 4);
  cvt4<<<(2048 * 1024 / 4 + 255) / 256, 256, 0, stream>>>(Wih, Wpre, 2048 * 1024 / 4);
  cvt4<<<(2048 * 2048 / 4 + 255) / 256, 256, 0, stream>>>(Whh, Wab, 2048 * 2048 / 4);
  cvt4<<<(2048 * 2048 / 4 + 255) / 256, 256, 0, stream>>>(Wt2, Wt2b, 2048 * 2048 / 4);
  split_wt1<<<(2048 * 768 + 255) / 256, 256, 0, stream>>>(Wt1, Wpre, Wab);
  biasprep<<<16, 256, 0, stream>>>(bih, bhh, bt1, biasp);
  init_h<<<(4096 * 2048 / 4) / 256, 256, 0, stream>>>(h, hb, hout);

  // precompute pre16 = f16(x @ [W_ih;W_t1x]^T + bias_pre)   (M=4096, N=4096, K=1024)
  {
    EpArgs e{};
    e.biasf = biasp;
    e.out_h = pre16;
    gemm_bt<0><<<dim3(32, 32), 256, 0, stream>>>(xb, Wpre, 4096, 4096, 1024, e);
  }

  const float dt = 1.0f / 3.0f;
  for (int s = 0; s < 3; ++s) {
    // k1 at h: EP1 then EP2 (h_mid = h + 0.5*dt*k1, f16 only)
    {
      EpArgs e{};
      e.pre16 = pre16; e.h16 = hb; e.out_d = dif16; e.out_h = t1b;
      gemm_bt<1><<<dim3(32, 32), 256, 0, stream>>>(hb, Wab, 4096, 4096, 2048, e);
    }
    {
      EpArgs e{};
      e.bt2 = bt2; e.diff = dif16; e.h_base = hout;
      e.coef = 0.5f * dt; e.out_f = nullptr; e.out_h = hmb;
      gemm_bt<2><<<dim3(32, 16), 256, 0, stream>>>(t1b, Wt2b, 4096, 2048, 2048, e);
    }
    // k2 at h_mid: EP1 then EP2 (h = h + dt*k2, fp32 + f16)
    {
      EpArgs e{};
      e.pre16 = pre16; e.h16 = hmb; e.out_d = dif16; e.out_h = t1b;
      gemm_bt<1><<<dim3(32, 32), 256, 0, stream>>>(hmb, Wab, 4096, 4096, 2048, e);
    }
    {
      EpArgs e{};
      e.bt2 = bt2; e.diff = dif16; e.h_base = hout;
      e.coef = dt; e.out_f = hout; e.out_h = hb;
      gemm_bt<2><<<dim3(32, 16), 256, 0, stream>>>(t1b, Wt2b, 4096, 2048, 2048, e);
    }
  }
}

// Round 4
// 945.284 us; speedup vs baseline: 1.6960x; 1.2965x over previous
//
#include <hip/hip_runtime.h>

// LiquidODECell: B=4096, D_IN=1024, H=2048, TAU_MIN=0.2, 3 RK2 steps.
// f16 MFMA GEMMs (fp32 accum), fused LDS-transposed epilogues.
// EP0/EP1 use a 256x256-tile, BK=32, triple-buffered phase-interleaved schedule
// (raw s_barrier + counted vmcnt + LDS XOR swizzle + setprio: T2/T3/T4/T5).
// EP2 stays on the proven 128x128 2-barrier kernel.

typedef _Float16 f16;
typedef __attribute__((ext_vector_type(4))) _Float16 f16x4;
typedef __attribute__((ext_vector_type(8))) _Float16 f16x8;
typedef __attribute__((ext_vector_type(4))) float f32x4;

#define TAU_MIN_F 0.2f

__device__ __forceinline__ float rcp_fast(float x) { return __builtin_amdgcn_rcpf(x); }
__device__ __forceinline__ float tanh_fast(float u) {
  float t = __expf(2.0f * u);
  return 1.0f - 2.0f * rcp_fast(t + 1.0f);
}
__device__ __forceinline__ float silu_fast(float u) {
  return u * rcp_fast(1.0f + __expf(-u));
}
__device__ __forceinline__ float softplus_fast(float u) {
  return fmaxf(u, 0.0f) + __logf(1.0f + __expf(-fabsf(u)));
}

__device__ __forceinline__ void glds16(const void* g, void* l) {
  __builtin_amdgcn_global_load_lds(
      (const __attribute__((address_space(1))) unsigned int*)g,
      (__attribute__((address_space(3))) unsigned int*)l,
      16, 0, 0);
}

// ---------------- prep kernels ----------------
__global__ void cvt4(const float* __restrict__ s, f16* __restrict__ d, int n4) {
  int i = blockIdx.x * 256 + threadIdx.x;
  if (i >= n4) return;
  float4 v = reinterpret_cast<const float4*>(s)[i];
  f16x4 o = {(_Float16)v.x, (_Float16)v.y, (_Float16)v.z, (_Float16)v.w};
  reinterpret_cast<f16x4*>(d)[i] = o;
}

__global__ void split_wt1(const float* __restrict__ Wt1, f16* __restrict__ Wpre,
                          f16* __restrict__ Wab) {
  int i = blockIdx.x * 256 + threadIdx.x;  // over 2048*768 float4 groups
  if (i >= 2048 * 768) return;
  int r = i / 768;
  int c4 = (i - r * 768) * 4;
  float4 v = reinterpret_cast<const float4*>(Wt1)[i];
  f16x4 o = {(_Float16)v.x, (_Float16)v.y, (_Float16)v.z, (_Float16)v.w};
  if (c4 < 1024)
    *reinterpret_cast<f16x4*>(Wpre + (size_t)(2048 + r) * 1024 + c4) = o;
  else
    *reinterpret_cast<f16x4*>(Wab + (size_t)(2048 + r) * 2048 + (c4 - 1024)) = o;
}

__global__ void biasprep(const float* __restrict__ bih, const float* __restrict__ bhh,
                         const float* __restrict__ bt1, float* __restrict__ biasp) {
  int i = blockIdx.x * 256 + threadIdx.x;
  if (i >= 4096) return;
  biasp[i] = (i < 2048) ? (bih[i] + bhh[i]) : bt1[i - 2048];
}

__global__ void init_h(const float* __restrict__ h, f16* __restrict__ hb,
                       float* __restrict__ hout) {
  int i = blockIdx.x * 256 + threadIdx.x;
  if (i >= 4096 * 2048 / 4) return;
  float4 v = reinterpret_cast<const float4*>(h)[i];
  reinterpret_cast<float4*>(hout)[i] = v;
  f16x4 o = {(_Float16)v.x, (_Float16)v.y, (_Float16)v.z, (_Float16)v.w};
  reinterpret_cast<f16x4*>(hb)[i] = o;
}

struct EpArgs {
  const float* biasf;   // EP0: bias_pre[N]
  const f16* pre16;     // EP1: pre [M,4096] f16
  const f16* h16;       // EP1: h this dynamics is evaluated at (f16)
  f16* out_d;           // EP1: diff f16
  f16* out_h;           // EP0: pre16 out; EP1: t1 f16; EP2: h' f16
  const float* bt2;     // EP2
  const f16* diff;      // EP2
  const float* h_base;  // EP2 (fp32 accumulator input)
  float* out_f;         // EP2: fp32 h' out (nullable)
  float coef;           // EP2 (0.5*dt or dt)
};

// ================= 256x256 phase-interleaved GEMM (EP0 / EP1) =================
// out[m][n] = sum_k A[m][k]*Bw[n][k]. 512 thr = 8 waves (2M x 4N), per-wave 128x64.
// BK=32. LDS: 3 buffers x (A 16KB + B 16KB) = 96 KB. XOR swizzle byte^=((row&3)<<4).
template <int EP>
__global__ __launch_bounds__(512, 2)
void gemm256(const f16* __restrict__ A, const f16* __restrict__ Bw,
             int N, int K, EpArgs ep) {
  __shared__ __align__(16) f16 SH[49152];  // 96 KB

  const int gx = gridDim.x;
  const int nwg = gx * gridDim.y;
  const int orig = blockIdx.y * gx + blockIdx.x;
  const int cpx = nwg >> 3;
  const int w = (orig & 7) * cpx + (orig >> 3);
  const int bm = (w % gx) * 256;
  const int bn = (w / gx) * 256;

  const int tid = threadIdx.x;
  const int lane = tid & 63;
  const int wid = tid >> 6;
  const int wr = wid >> 2;  // 0..1
  const int wc = wid & 3;   // 0..3

  char* SHb = (char*)SH;

  // ---- staging invariants: call j covers rows j*128..+127; 64B rows ----
  const int srow = wid * 16 + (lane >> 2);                 // 0..127
  const int skof = ((lane & 3) ^ ((lane >> 2) & 3)) << 4;  // pre-swizzled src chunk
  const char* Ag0 = (const char*)A + (size_t)(bm + srow) * K * 2 + skof;
  const char* Ag1 = Ag0 + (size_t)128 * K * 2;
  const char* Bg0 = (const char*)Bw + (size_t)(bn + srow) * K * 2 + skof;
  const char* Bg1 = Bg0 + (size_t)128 * K * 2;
  const int dst = wid * 1024;  // wave-uniform; HW adds lane*16

  // ---- fragment read offsets (swizzled) ----
  const int fr = lane & 15;
  const int rxor = ((lane >> 4) ^ (fr & 3)) << 4;
  const int abase = (wr * 128 + fr) * 64 + rxor;           // + mi*1024 + buf*32768
  const int bbase = 16384 + (wc * 64 + fr) * 64 + rxor;    // + ni*1024 + buf*32768

  f32x4 acc[8][4] = {};
  const int NT = K >> 5;

  auto STAGE_A = [&](int t, int b) {
    const size_t kby = (size_t)t * 64;
    char* base = SHb + b * 32768;
    glds16(Ag0 + kby, base + dst);
    glds16(Ag1 + kby, base + 8192 + dst);
  };
  auto STAGE_B = [&](int t, int b) {
    const size_t kby = (size_t)t * 64;
    char* base = SHb + b * 32768;
    glds16(Bg0 + kby, base + 16384 + dst);
    glds16(Bg1 + kby, base + 24576 + dst);
  };

  // prologue: stage tiles 0,1 (8 loads/wave outstanding)
  STAGE_A(0, 0); STAGE_B(0, 0);
  STAGE_A(1, 1); STAGE_B(1, 1);

  int b = 0;
  for (int t = 0; t < NT - 1; ++t) {
    const int b2 = (b == 0) ? 2 : b - 1;  // (b+2)%3
    asm volatile("s_waitcnt vmcnt(4)" ::: "memory");  // tile t landed (t+1 in flight)
    __builtin_amdgcn_s_barrier();
    __builtin_amdgcn_sched_barrier(0);
    const char* bufp = SHb + b * 32768;
    // ---- phase 0: read A[0..3]+B[0..3], stage A(t+2), MFMA quad 0 ----
    f16x8 af[4], bf[4];
#pragma unroll
    for (int i = 0; i < 4; ++i) af[i] = *reinterpret_cast<const f16x8*>(bufp + abase + i * 1024);
#pragma unroll
    for (int i = 0; i < 4; ++i) bf[i] = *reinterpret_cast<const f16x8*>(bufp + bbase + i * 1024);
    if (t + 2 < NT) STAGE_A(t + 2, b2);
    __builtin_amdgcn_s_barrier();
    __builtin_amdgcn_sched_barrier(0);
    asm volatile("s_waitcnt lgkmcnt(0)" ::: "memory");
    __builtin_amdgcn_sched_barrier(0);
    __builtin_amdgcn_s_setprio(1);
#pragma unroll
    for (int mi = 0; mi < 4; ++mi)
#pragma unroll
      for (int ni = 0; ni < 4; ++ni)
        acc[mi][ni] = __builtin_amdgcn_mfma_f32_16x16x32_f16(af[mi], bf[ni], acc[mi][ni], 0, 0, 0);
    __builtin_amdgcn_s_setprio(0);
    // ---- phase 1: read A[4..7], stage B(t+2), MFMA quad 1 ----
    f16x8 ag[4];
#pragma unroll
    for (int i = 0; i < 4; ++i) ag[i] = *reinterpret_cast<const f16x8*>(bufp + abase + (4 + i) * 1024);
    if (t + 2 < NT) STAGE_B(t + 2, b2);
    __builtin_amdgcn_s_barrier();
    __builtin_amdgcn_sched_barrier(0);
    asm volatile("s_waitcnt lgkmcnt(0)" ::: "memory");
    __builtin_amdgcn_sched_barrier(0);
    __builtin_amdgcn_s_setprio(1);
#pragma unroll
    for (int mi = 0; mi < 4; ++mi)
#pragma unroll
      for (int ni = 0; ni < 4; ++ni)
        acc[4 + mi][ni] = __builtin_amdgcn_mfma_f32_16x16x32_f16(ag[mi], bf[ni], acc[4 + mi][ni], 0, 0, 0);
    __builtin_amdgcn_s_setprio(0);
    b = (b == 2) ? 0 : b + 1;
  }
  // ---- peeled last tile: full drain, no staging ----
  {
    asm volatile("s_waitcnt vmcnt(0)" ::: "memory");
    __builtin_amdgcn_s_barrier();
    __builtin_amdgcn_sched_barrier(0);
    const char* bufp = SHb + b * 32768;
    f16x8 af[4], bf[4];
#pragma unroll
    for (int i = 0; i < 4; ++i) af[i] = *reinterpret_cast<const f16x8*>(bufp + abase + i * 1024);
#pragma unroll
    for (int i = 0; i < 4; ++i) bf[i] = *reinterpret_cast<const f16x8*>(bufp + bbase + i * 1024);
#pragma unroll
    for (int mi = 0; mi < 4; ++mi)
#pragma unroll
      for (int ni = 0; ni < 4; ++ni)
        acc[mi][ni] = __builtin_amdgcn_mfma_f32_16x16x32_f16(af[mi], bf[ni], acc[mi][ni], 0, 0, 0);
    f16x8 ag[4];
#pragma unroll
    for (int i = 0; i < 4; ++i) ag[i] = *reinterpret_cast<const f16x8*>(bufp + abase + (4 + i) * 1024);
#pragma unroll
    for (int mi = 0; mi < 4; ++mi)
#pragma unroll
      for (int ni = 0; ni < 4; ++ni)
        acc[4 + mi][ni] = __builtin_amdgcn_mfma_f32_16x16x32_f16(ag[mi], bf[ni], acc[4 + mi][ni], 0, 0, 0);
  }
  __syncthreads();  // full drain before LDS reuse by epilogue

  // ---- epilogue via per-wave LDS transpose ----
  f16* tb = SH + wid * 1088;  // 16x68 f16 per wave
  const int er = (lane >> 4) * 4;
  const int ec = lane & 15;
  const int rr = lane >> 3;
  const int cc = (lane & 7) * 8;
  const int colbase = bn + wc * 64;

#pragma unroll
  for (int mi = 0; mi < 8; ++mi) {
#pragma unroll
    for (int ni = 0; ni < 4; ++ni)
#pragma unroll
      for (int j = 0; j < 4; ++j)
        tb[(er + j) * 68 + ni * 16 + ec] = (f16)acc[mi][ni][j];
#pragma unroll
    for (int it = 0; it < 2; ++it) {
      const int row = rr + it * 8;
      const int gm = bm + wr * 128 + mi * 16 + row;
      const int gn = colbase + cc;
      f16x8 v = *reinterpret_cast<const f16x8*>(tb + row * 68 + cc);
      if constexpr (EP == 0) {
        float4 b0 = *reinterpret_cast<const float4*>(ep.biasf + gn);
        float4 b1 = *reinterpret_cast<const float4*>(ep.biasf + gn + 4);
        f16x8 o;
        o[0] = (f16)((float)v[0] + b0.x); o[1] = (f16)((float)v[1] + b0.y);
        o[2] = (f16)((float)v[2] + b0.z); o[3] = (f16)((float)v[3] + b0.w);
        o[4] = (f16)((float)v[4] + b1.x); o[5] = (f16)((float)v[5] + b1.y);
        o[6] = (f16)((float)v[6] + b1.z); o[7] = (f16)((float)v[7] + b1.w);
        *reinterpret_cast<f16x8*>(ep.out_h + (size_t)gm * N + gn) = o;
      } else {
        f16x8 pr = *reinterpret_cast<const f16x8*>(ep.pre16 + (size_t)gm * 4096 + gn);
        if (colbase < 2048) {
          f16x8 hh = *reinterpret_cast<const f16x8*>(ep.h16 + (size_t)gm * 2048 + gn);
          f16x8 o;
#pragma unroll
          for (int k = 0; k < 8; ++k) {
            float u = (float)v[k] + (float)pr[k];
            o[k] = (f16)(tanh_fast(u) - (float)hh[k]);
          }
          *reinterpret_cast<f16x8*>(ep.out_d + (size_t)gm * 2048 + gn) = o;
        } else {
          f16x8 o;
#pragma unroll
          for (int k = 0; k < 8; ++k) {
            float u = (float)v[k] + (float)pr[k];
            o[k] = (f16)silu_fast(u);
          }
          *reinterpret_cast<f16x8*>(ep.out_h + (size_t)gm * 2048 + (gn - 2048)) = o;
        }
      }
    }
  }
}

// ================= 128x128 2-barrier GEMM (EP2) =================
template <int EP>
__global__ __launch_bounds__(256)
void gemm_bt(const f16* __restrict__ A, const f16* __restrict__ Bw,
             int M, int N, int K, EpArgs ep) {
  __shared__ __align__(16) f16 SH[8192];

  const int gx = gridDim.x;
  const int nwg = gx * gridDim.y;
  const int orig = blockIdx.y * gx + blockIdx.x;
  const int cpx = nwg >> 3;
  const int w = (orig & 7) * cpx + (orig >> 3);
  const int bm = (w % gx) * 128;
  const int bn = (w / gx) * 128;

  const int tid = threadIdx.x;
  const int lane = tid & 63;
  const int wid = tid >> 6;
  const int wm = (wid >> 1) * 64;
  const int wn = (wid & 1) * 64;

  char* Asb = (char*)SH;
  char* Bsb = (char*)(SH + 4096);

  const int off0 = wid * 2048 + lane * 16;
  const int off1 = off0 + 1024;
  const int row0 = off0 >> 6, cb0 = off0 & 63;
  const int row1 = off1 >> 6, cb1 = off1 & 63;
  const char* Ag0 = (const char*)(A + (size_t)(bm + row0) * K) + cb0;
  const char* Ag1 = (const char*)(A + (size_t)(bm + row1) * K) + cb1;
  const char* Bg0 = (const char*)(Bw + (size_t)(bn + row0) * K) + cb0;
  const char* Bg1 = (const char*)(Bw + (size_t)(bn + row1) * K) + cb1;
  char* ldsA0 = Asb + wid * 2048;
  char* ldsA1 = Asb + wid * 2048 + 1024;
  char* ldsB0 = Bsb + wid * 2048;
  char* ldsB1 = Bsb + wid * 2048 + 1024;

  const int fr = lane & 15;
  const int kb = (lane >> 4) * 16;
  int aoff[4], boff[4];
#pragma unroll
  for (int i = 0; i < 4; ++i) {
    aoff[i] = (wm + i * 16 + fr) * 64 + kb;
    boff[i] = (wn + i * 16 + fr) * 64 + kb;
  }

  f32x4 acc[4][4] = {};
  const int nk = K >> 5;
  for (int kt = 0; kt < nk; ++kt) {
    const size_t kby = (size_t)kt * 64;
    glds16(Ag0 + kby, ldsA0);
    glds16(Ag1 + kby, ldsA1);
    glds16(Bg0 + kby, ldsB0);
    glds16(Bg1 + kby, ldsB1);
    __syncthreads();

    f16x8 af[4], bf[4];
#pragma unroll
    for (int i = 0; i < 4; ++i) af[i] = *reinterpret_cast<const f16x8*>(Asb + aoff[i]);
#pragma unroll
    for (int i = 0; i < 4; ++i) bf[i] = *reinterpret_cast<const f16x8*>(Bsb + boff[i]);

#pragma unroll
    for (int mi = 0; mi < 4; ++mi)
#pragma unroll
      for (int ni = 0; ni < 4; ++ni)
        acc[mi][ni] = __builtin_amdgcn_mfma_f32_16x16x32_f16(af[mi], bf[ni], acc[mi][ni], 0, 0, 0);

    __syncthreads();
  }

  f16* tb = SH + wid * 1088;
  const int er = (lane >> 4) * 4;
  const int ec = lane & 15;
  const int rr = lane >> 3;
  const int cc = (lane & 7) * 8;
  const int colbase = bn + wn;

#pragma unroll
  for (int mi = 0; mi < 4; ++mi) {
#pragma unroll
    for (int ni = 0; ni < 4; ++ni)
#pragma unroll
      for (int j = 0; j < 4; ++j)
        tb[(er + j) * 68 + ni * 16 + ec] = (f16)acc[mi][ni][j];
#pragma unroll
    for (int it = 0; it < 2; ++it) {
      const int row = rr + it * 8;
      const int gm = bm + wm + mi * 16 + row;
      const int gn = colbase + cc;
      f16x8 v = *reinterpret_cast<const f16x8*>(tb + row * 68 + cc);
      const size_t idx = (size_t)gm * 2048 + gn;
      float4 b0 = *reinterpret_cast<const float4*>(ep.bt2 + gn);
      float4 b1 = *reinterpret_cast<const float4*>(ep.bt2 + gn + 4);
      f16x8 df = *reinterpret_cast<const f16x8*>(ep.diff + idx);
      float4 h0 = *reinterpret_cast<const float4*>(ep.h_base + idx);
      float4 h1 = *reinterpret_cast<const float4*>(ep.h_base + idx + 4);
      float bb[8] = {b0.x, b0.y, b0.z, b0.w, b1.x, b1.y, b1.z, b1.w};
      float hb8[8] = {h0.x, h0.y, h0.z, h0.w, h1.x, h1.y, h1.z, h1.w};
      f16x8 o16;
      float on[8];
#pragma unroll
      for (int k = 0; k < 8; ++k) {
        float u = (float)v[k] + bb[k];
        float tau = softplus_fast(u) + TAU_MIN_F;
        float hn = hb8[k] + ep.coef * ((float)df[k] * rcp_fast(tau));
        on[k] = hn;
        o16[k] = (f16)hn;
      }
      *reinterpret_cast<f16x8*>(ep.out_h + idx) = o16;
      if (ep.out_f) {
        float4 o0 = {on[0], on[1], on[2], on[3]};
        float4 o1 = {on[4], on[5], on[6], on[7]};
        *reinterpret_cast<float4*>(ep.out_f + idx) = o0;
        *reinterpret_cast<float4*>(ep.out_f + idx + 4) = o1;
      }
    }
  }
}

// ---------------- launch ----------------
extern "C" void kernel_launch(void* const* d_in, const int* in_sizes, int n_in,
                              void* d_out, int out_size, void* d_ws, size_t ws_size,
                              hipStream_t stream) {
  const float* x   = (const float*)d_in[0];
  const float* h   = (const float*)d_in[1];
  const float* Wih = (const float*)d_in[2];
  const float* bih = (const float*)d_in[3];
  const float* Whh = (const float*)d_in[4];
  const float* bhh = (const float*)d_in[5];
  const float* Wt1 = (const float*)d_in[6];
  const float* bt1 = (const float*)d_in[7];
  const float* Wt2 = (const float*)d_in[8];
  const float* bt2 = (const float*)d_in[9];
  float* hout = (float*)d_out;

  char* p = (char*)d_ws;
  auto alloc = [&](size_t bytes) {
    char* r = p;
    p += (bytes + 255) & ~(size_t)255;
    return r;
  };
  f16* xb    = (f16*)alloc((size_t)4096 * 1024 * 2);
  f16* Wpre  = (f16*)alloc((size_t)4096 * 1024 * 2);
  f16* Wab   = (f16*)alloc((size_t)4096 * 2048 * 2);
  f16* Wt2b  = (f16*)alloc((size_t)2048 * 2048 * 2);
  f16* hb    = (f16*)alloc((size_t)4096 * 2048 * 2);
  f16* hmb   = (f16*)alloc((size_t)4096 * 2048 * 2);
  f16* t1b   = (f16*)alloc((size_t)4096 * 2048 * 2);
  f16* pre16 = (f16*)alloc((size_t)4096 * 4096 * 2);
  f16* dif16 = (f16*)alloc((size_t)4096 * 2048 * 2);
  float* biasp = (float*)alloc(4096 * 4);

  cvt4<<<(4096 * 1024 / 4 + 255) / 256, 256, 0, stream>>>(x, xb, 4096 * 1024 / 4);
  cvt4<<<(2048 * 1024 / 4 + 255) / 256, 256, 0, stream>>>(Wih, Wpre, 2048 * 1024 / 4);
  cvt4<<<(2048 * 2048 / 4 + 255) / 256, 256, 0, stream>>>(Whh, Wab, 2048 * 2048 / 4);
  cvt4<<<(2048 * 2048 / 4 + 255) / 256, 256, 0, stream>>>(Wt2, Wt2b, 2048 * 2048 / 4);
  split_wt1<<<(2048 * 768 + 255) / 256, 256, 0, stream>>>(Wt1, Wpre, Wab);
  biasprep<<<16, 256, 0, stream>>>(bih, bhh, bt1, biasp);
  init_h<<<(4096 * 2048 / 4) / 256, 256, 0, stream>>>(h, hb, hout);

  // pre16 = f16(x @ [W_ih;W_t1x]^T + bias_pre)   (M=4096, N=4096, K=1024)
  {
    EpArgs e{};
    e.biasf = biasp;
    e.out_h = pre16;
    gemm256<0><<<dim3(16, 16), 512, 0, stream>>>(xb, Wpre, 4096, 1024, e);
  }

  const float dt = 1.0f / 3.0f;
  for (int s = 0; s < 3; ++s) {
    {
      EpArgs e{};
      e.pre16 = pre16; e.h16 = hb; e.out_d = dif16; e.out_h = t1b;
      gemm256<1><<<dim3(16, 16), 512, 0, stream>>>(hb, Wab, 4096, 2048, e);
    }
    {
      EpArgs e{};
      e.bt2 = bt2; e.diff = dif16; e.h_base = hout;
      e.coef = 0.5f * dt; e.out_f = nullptr; e.out_h = hmb;
      gemm_bt<2><<<dim3(32, 16), 256, 0, stream>>>(t1b, Wt2b, 4096, 2048, 2048, e);
    }
    {
      EpArgs e{};
      e.pre16 = pre16; e.h16 = hmb; e.out_d = dif16; e.out_h = t1b;
      gemm256<1><<<dim3(16, 16), 512, 0, stream>>>(hmb, Wab, 4096, 2048, e);
    }
    {
      EpArgs e{};
      e.bt2 = bt2; e.diff = dif16; e.h_base = hout;
      e.coef = dt; e.out_f = hout; e.out_h = hb;
      gemm_bt<2><<<dim3(32, 16), 256, 0, stream>>>(t1b, Wt2b, 4096, 2048, 2048, e);
    }
  }
}

// Round 5
// 839.503 us; speedup vs baseline: 1.9097x; 1.1260x over previous
//
#include <hip/hip_runtime.h>

// LiquidODECell: B=4096, D_IN=1024, H=2048, TAU_MIN=0.2, 3 RK2 steps.
// f16 MFMA GEMMs (fp32 accum), fused LDS-transposed epilogues.
// All GEMMs use the triple-buffered phase-interleaved schedule (raw s_barrier +
// counted vmcnt + setprio). gemmT<EP, BMB, BNB>: tile = (BMB*128) x (BNB*128).
//   EP0/EP1: 256x256 (grid 16x16), EP2: 256x128 (grid 16x16 = 1 block/CU).
// h is kept in f16 across ODE steps; fp32 h written only by the final EP2.

typedef _Float16 f16;
typedef __attribute__((ext_vector_type(4))) _Float16 f16x4;
typedef __attribute__((ext_vector_type(8))) _Float16 f16x8;
typedef __attribute__((ext_vector_type(4))) float f32x4;

#define TAU_MIN_F 0.2f

__device__ __forceinline__ float rcp_fast(float x) { return __builtin_amdgcn_rcpf(x); }
__device__ __forceinline__ float tanh_fast(float u) {
  float t = __expf(2.0f * u);
  return 1.0f - 2.0f * rcp_fast(t + 1.0f);
}
__device__ __forceinline__ float silu_fast(float u) {
  return u * rcp_fast(1.0f + __expf(-u));
}
__device__ __forceinline__ float softplus_fast(float u) {
  return fmaxf(u, 0.0f) + __logf(1.0f + __expf(-fabsf(u)));
}

__device__ __forceinline__ void glds16(const void* g, void* l) {
  __builtin_amdgcn_global_load_lds(
      (const __attribute__((address_space(1))) unsigned int*)g,
      (__attribute__((address_space(3))) unsigned int*)l,
      16, 0, 0);
}

// ---------------- prep kernels ----------------
__global__ void cvt4(const float* __restrict__ s, f16* __restrict__ d, int n4) {
  int i = blockIdx.x * 256 + threadIdx.x;
  if (i >= n4) return;
  float4 v = reinterpret_cast<const float4*>(s)[i];
  f16x4 o = {(_Float16)v.x, (_Float16)v.y, (_Float16)v.z, (_Float16)v.w};
  reinterpret_cast<f16x4*>(d)[i] = o;
}

__global__ void split_wt1(const float* __restrict__ Wt1, f16* __restrict__ Wpre,
                          f16* __restrict__ Wab) {
  int i = blockIdx.x * 256 + threadIdx.x;  // over 2048*768 float4 groups
  if (i >= 2048 * 768) return;
  int r = i / 768;
  int c4 = (i - r * 768) * 4;
  float4 v = reinterpret_cast<const float4*>(Wt1)[i];
  f16x4 o = {(_Float16)v.x, (_Float16)v.y, (_Float16)v.z, (_Float16)v.w};
  if (c4 < 1024)
    *reinterpret_cast<f16x4*>(Wpre + (size_t)(2048 + r) * 1024 + c4) = o;
  else
    *reinterpret_cast<f16x4*>(Wab + (size_t)(2048 + r) * 2048 + (c4 - 1024)) = o;
}

__global__ void biasprep(const float* __restrict__ bih, const float* __restrict__ bhh,
                         const float* __restrict__ bt1, float* __restrict__ biasp) {
  int i = blockIdx.x * 256 + threadIdx.x;
  if (i >= 4096) return;
  biasp[i] = (i < 2048) ? (bih[i] + bhh[i]) : bt1[i - 2048];
}

struct EpArgs {
  const float* biasf;   // EP0: bias_pre[N]
  const f16* pre16;     // EP1: pre [M,4096] f16
  const f16* h16;       // EP1: h this dynamics is evaluated at (f16)
  f16* out_d;           // EP1: diff f16
  f16* out_h;           // EP0: pre16 out; EP1: t1 f16; EP2: h' f16
  const float* bt2;     // EP2
  const f16* diff;      // EP2
  const f16* hb16;      // EP2: RK2 base h (f16)
  float* out_f;         // EP2: fp32 h' out (nullable; final step only)
  float coef;           // EP2 (0.5*dt or dt)
};

// ================= phase-interleaved GEMM, tile (BMB*128) x (BNB*128) =================
// out[m][n] = sum_k A[m][k]*Bw[n][k]. 512 thr = 8 waves (2M x 4N).
// BK=32 (64B rows). LDS: 3 buffers x (BMB+BNB)*8KB. Counted vmcnt = L = BMB+BNB.
template <int EP, int BMB, int BNB>
__global__ __launch_bounds__(512, 2)
void gemmT(const f16* __restrict__ A, const f16* __restrict__ Bw,
           int N, int K, EpArgs ep) {
  constexpr int MI = BMB * 4;               // 16-row frags per wave (M)
  constexpr int NI = BNB * 2;               // 16-col frags per wave (N)
  constexpr int L = BMB + BNB;              // glds16 per wave per K-tile
  constexpr int BUFB = (BMB + BNB) * 8192;  // bytes per LDS buffer
  constexpr int BOFF = BMB * 8192;          // B offset within buffer
  __shared__ __align__(16) char SH[BUFB * 3];

  const int gx = gridDim.x;
  const int nwg = gx * gridDim.y;
  const int orig = blockIdx.y * gx + blockIdx.x;
  const int cpx = nwg >> 3;
  const int w = (orig & 7) * cpx + (orig >> 3);
  const int bm = (w % gx) * (BMB * 128);
  const int bn = (w / gx) * (BNB * 128);

  const int tid = threadIdx.x;
  const int lane = tid & 63;
  const int wid = tid >> 6;
  const int wr = wid >> 2;  // 0..1
  const int wc = wid & 3;   // 0..3

  // ---- staging: instr j covers rows j*128..+127 of its tile; 64B rows ----
  const int srow = wid * 16 + (lane >> 2);                 // 0..127
  const int skof = ((lane & 3) ^ ((lane >> 2) & 3)) << 4;  // pre-swizzled src chunk
  const char* Ag[BMB];
  const char* Bg[BNB];
#pragma unroll
  for (int j = 0; j < BMB; ++j)
    Ag[j] = (const char*)A + (size_t)(bm + j * 128 + srow) * K * 2 + skof;
#pragma unroll
  for (int j = 0; j < BNB; ++j)
    Bg[j] = (const char*)Bw + (size_t)(bn + j * 128 + srow) * K * 2 + skof;
  const int dst = wid * 1024;  // wave-uniform; HW adds lane*16

  // ---- fragment read offsets (swizzled) ----
  const int fr = lane & 15;
  const int rxor = ((lane >> 4) ^ (fr & 3)) << 4;
  const int abase = (wr * (BMB * 64) + fr) * 64 + rxor;
  const int bbase = BOFF + (wc * (BNB * 32) + fr) * 64 + rxor;

  f32x4 acc[MI][NI] = {};
  const int NT = K >> 5;

  auto STAGE_A = [&](int t, int b) {
    const size_t kby = (size_t)t * 64;
    char* base = SH + b * BUFB;
#pragma unroll
    for (int j = 0; j < BMB; ++j) glds16(Ag[j] + kby, base + j * 8192 + dst);
  };
  auto STAGE_B = [&](int t, int b) {
    const size_t kby = (size_t)t * 64;
    char* base = SH + b * BUFB;
#pragma unroll
    for (int j = 0; j < BNB; ++j) glds16(Bg[j] + kby, base + BOFF + j * 8192 + dst);
  };

  // prologue: stage tiles 0,1 (2L loads/wave outstanding)
  STAGE_A(0, 0); STAGE_B(0, 0);
  STAGE_A(1, 1); STAGE_B(1, 1);

  int b = 0;
  for (int t = 0; t < NT - 1; ++t) {
    const int b2 = (b == 0) ? 2 : b - 1;  // (b+2)%3
    // tile t landed; tile t+1's L loads may remain in flight
    if constexpr (L == 4) asm volatile("s_waitcnt vmcnt(4)" ::: "memory");
    else                  asm volatile("s_waitcnt vmcnt(3)" ::: "memory");
    __builtin_amdgcn_s_barrier();
    __builtin_amdgcn_sched_barrier(0);
    const char* bufp = SH + b * BUFB;
    // ---- phase 0: read A-half0 + all B, stage A(t+2), MFMA half 0 ----
    f16x8 af[MI / 2], bf[NI];
#pragma unroll
    for (int i = 0; i < MI / 2; ++i)
      af[i] = *reinterpret_cast<const f16x8*>(bufp + abase + i * 1024);
#pragma unroll
    for (int i = 0; i < NI; ++i)
      bf[i] = *reinterpret_cast<const f16x8*>(bufp + bbase + i * 1024);
    if (t + 2 < NT) STAGE_A(t + 2, b2);
    __builtin_amdgcn_s_barrier();
    __builtin_amdgcn_sched_barrier(0);
    asm volatile("s_waitcnt lgkmcnt(0)" ::: "memory");
    __builtin_amdgcn_sched_barrier(0);
    __builtin_amdgcn_s_setprio(1);
#pragma unroll
    for (int mi = 0; mi < MI / 2; ++mi)
#pragma unroll
      for (int ni = 0; ni < NI; ++ni)
        acc[mi][ni] = __builtin_amdgcn_mfma_f32_16x16x32_f16(af[mi], bf[ni], acc[mi][ni], 0, 0, 0);
    __builtin_amdgcn_s_setprio(0);
    // ---- phase 1: read A-half1, stage B(t+2), MFMA half 1 ----
    f16x8 ag[MI / 2];
#pragma unroll
    for (int i = 0; i < MI / 2; ++i)
      ag[i] = *reinterpret_cast<const f16x8*>(bufp + abase + (MI / 2 + i) * 1024);
    if (t + 2 < NT) STAGE_B(t + 2, b2);
    __builtin_amdgcn_s_barrier();
    __builtin_amdgcn_sched_barrier(0);
    asm volatile("s_waitcnt lgkmcnt(0)" ::: "memory");
    __builtin_amdgcn_sched_barrier(0);
    __builtin_amdgcn_s_setprio(1);
#pragma unroll
    for (int mi = 0; mi < MI / 2; ++mi)
#pragma unroll
      for (int ni = 0; ni < NI; ++ni)
        acc[MI / 2 + mi][ni] =
            __builtin_amdgcn_mfma_f32_16x16x32_f16(ag[mi], bf[ni], acc[MI / 2 + mi][ni], 0, 0, 0);
    __builtin_amdgcn_s_setprio(0);
    b = (b == 2) ? 0 : b + 1;
  }
  // ---- peeled last tile: full drain, no staging ----
  {
    asm volatile("s_waitcnt vmcnt(0)" ::: "memory");
    __builtin_amdgcn_s_barrier();
    __builtin_amdgcn_sched_barrier(0);
    const char* bufp = SH + b * BUFB;
    f16x8 af[MI / 2], bf[NI];
#pragma unroll
    for (int i = 0; i < MI / 2; ++i)
      af[i] = *reinterpret_cast<const f16x8*>(bufp + abase + i * 1024);
#pragma unroll
    for (int i = 0; i < NI; ++i)
      bf[i] = *reinterpret_cast<const f16x8*>(bufp + bbase + i * 1024);
#pragma unroll
    for (int mi = 0; mi < MI / 2; ++mi)
#pragma unroll
      for (int ni = 0; ni < NI; ++ni)
        acc[mi][ni] = __builtin_amdgcn_mfma_f32_16x16x32_f16(af[mi], bf[ni], acc[mi][ni], 0, 0, 0);
    f16x8 ag[MI / 2];
#pragma unroll
    for (int i = 0; i < MI / 2; ++i)
      ag[i] = *reinterpret_cast<const f16x8*>(bufp + abase + (MI / 2 + i) * 1024);
#pragma unroll
    for (int mi = 0; mi < MI / 2; ++mi)
#pragma unroll
      for (int ni = 0; ni < NI; ++ni)
        acc[MI / 2 + mi][ni] =
            __builtin_amdgcn_mfma_f32_16x16x32_f16(ag[mi], bf[ni], acc[MI / 2 + mi][ni], 0, 0, 0);
  }
  __syncthreads();  // full drain before LDS reuse by epilogue

  // ---- epilogue via per-wave LDS transpose (coalesced global I/O) ----
  constexpr int WNC = BNB * 32;   // per-wave output cols
  constexpr int TBS = WNC + 4;    // padded LDS row stride (f16)
  constexpr int LPR = BNB * 4;    // lanes per row on readback
  f16* tb = (f16*)SH + wid * 16 * TBS;
  const int er = (lane >> 4) * 4;
  const int ec = lane & 15;
  const int rr = lane / LPR;
  const int cc = (lane % LPR) * 8;
  const int colbase = bn + wc * WNC;

#pragma unroll
  for (int mi = 0; mi < MI; ++mi) {
#pragma unroll
    for (int ni = 0; ni < NI; ++ni)
#pragma unroll
      for (int j = 0; j < 4; ++j)
        tb[(er + j) * TBS + ni * 16 + ec] = (f16)acc[mi][ni][j];
    // same-wave DS ordering: reads observe the writes above
#pragma unroll
    for (int it = 0; it < BNB; ++it) {
      const int row = rr + it * (16 / BNB);
      const int gm = bm + wr * (BMB * 64) + mi * 16 + row;
      const int gn = colbase + cc;
      f16x8 v = *reinterpret_cast<const f16x8*>(tb + row * TBS + cc);
      if constexpr (EP == 0) {
        float4 b0 = *reinterpret_cast<const float4*>(ep.biasf + gn);
        float4 b1 = *reinterpret_cast<const float4*>(ep.biasf + gn + 4);
        f16x8 o;
        o[0] = (f16)((float)v[0] + b0.x); o[1] = (f16)((float)v[1] + b0.y);
        o[2] = (f16)((float)v[2] + b0.z); o[3] = (f16)((float)v[3] + b0.w);
        o[4] = (f16)((float)v[4] + b1.x); o[5] = (f16)((float)v[5] + b1.y);
        o[6] = (f16)((float)v[6] + b1.z); o[7] = (f16)((float)v[7] + b1.w);
        *reinterpret_cast<f16x8*>(ep.out_h + (size_t)gm * N + gn) = o;
      } else if constexpr (EP == 1) {
        f16x8 pr = *reinterpret_cast<const f16x8*>(ep.pre16 + (size_t)gm * 4096 + gn);
        if (colbase < 2048) {
          f16x8 hh = *reinterpret_cast<const f16x8*>(ep.h16 + (size_t)gm * 2048 + gn);
          f16x8 o;
#pragma unroll
          for (int k = 0; k < 8; ++k) {
            float u = (float)v[k] + (float)pr[k];
            o[k] = (f16)(tanh_fast(u) - (float)hh[k]);
          }
          *reinterpret_cast<f16x8*>(ep.out_d + (size_t)gm * 2048 + gn) = o;
        } else {
          f16x8 o;
#pragma unroll
          for (int k = 0; k < 8; ++k) {
            float u = (float)v[k] + (float)pr[k];
            o[k] = (f16)silu_fast(u);
          }
          *reinterpret_cast<f16x8*>(ep.out_h + (size_t)gm * 2048 + (gn - 2048)) = o;
        }
      } else {
        const size_t idx = (size_t)gm * 2048 + gn;
        float4 b0 = *reinterpret_cast<const float4*>(ep.bt2 + gn);
        float4 b1 = *reinterpret_cast<const float4*>(ep.bt2 + gn + 4);
        f16x8 df = *reinterpret_cast<const f16x8*>(ep.diff + idx);
        f16x8 hbv = *reinterpret_cast<const f16x8*>(ep.hb16 + idx);
        float bb[8] = {b0.x, b0.y, b0.z, b0.w, b1.x, b1.y, b1.z, b1.w};
        f16x8 o16;
        float on[8];
#pragma unroll
        for (int k = 0; k < 8; ++k) {
          float u = (float)v[k] + bb[k];
          float tau = softplus_fast(u) + TAU_MIN_F;
          float hn = (float)hbv[k] + ep.coef * ((float)df[k] * rcp_fast(tau));
          on[k] = hn;
          o16[k] = (f16)hn;
        }
        *reinterpret_cast<f16x8*>(ep.out_h + idx) = o16;
        if (ep.out_f) {
          float4 o0 = {on[0], on[1], on[2], on[3]};
          float4 o1 = {on[4], on[5], on[6], on[7]};
          *reinterpret_cast<float4*>(ep.out_f + idx) = o0;
          *reinterpret_cast<float4*>(ep.out_f + idx + 4) = o1;
        }
      }
    }
  }
}

// ---------------- launch ----------------
extern "C" void kernel_launch(void* const* d_in, const int* in_sizes, int n_in,
                              void* d_out, int out_size, void* d_ws, size_t ws_size,
                              hipStream_t stream) {
  const float* x   = (const float*)d_in[0];
  const float* h   = (const float*)d_in[1];
  const float* Wih = (const float*)d_in[2];
  const float* bih = (const float*)d_in[3];
  const float* Whh = (const float*)d_in[4];
  const float* bhh = (const float*)d_in[5];
  const float* Wt1 = (const float*)d_in[6];
  const float* bt1 = (const float*)d_in[7];
  const float* Wt2 = (const float*)d_in[8];
  const float* bt2 = (const float*)d_in[9];
  float* hout = (float*)d_out;

  char* p = (char*)d_ws;
  auto alloc = [&](size_t bytes) {
    char* r = p;
    p += (bytes + 255) & ~(size_t)255;
    return r;
  };
  f16* xb    = (f16*)alloc((size_t)4096 * 1024 * 2);
  f16* Wpre  = (f16*)alloc((size_t)4096 * 1024 * 2);
  f16* Wab   = (f16*)alloc((size_t)4096 * 2048 * 2);
  f16* Wt2b  = (f16*)alloc((size_t)2048 * 2048 * 2);
  f16* hb    = (f16*)alloc((size_t)4096 * 2048 * 2);
  f16* hmb   = (f16*)alloc((size_t)4096 * 2048 * 2);
  f16* t1b   = (f16*)alloc((size_t)4096 * 2048 * 2);
  f16* pre16 = (f16*)alloc((size_t)4096 * 4096 * 2);
  f16* dif16 = (f16*)alloc((size_t)4096 * 2048 * 2);
  float* biasp = (float*)alloc(4096 * 4);

  cvt4<<<(4096 * 1024 / 4 + 255) / 256, 256, 0, stream>>>(x, xb, 4096 * 1024 / 4);
  cvt4<<<(2048 * 1024 / 4 + 255) / 256, 256, 0, stream>>>(Wih, Wpre, 2048 * 1024 / 4);
  cvt4<<<(2048 * 2048 / 4 + 255) / 256, 256, 0, stream>>>(Whh, Wab, 2048 * 2048 / 4);
  cvt4<<<(2048 * 2048 / 4 + 255) / 256, 256, 0, stream>>>(Wt2, Wt2b, 2048 * 2048 / 4);
  cvt4<<<(4096 * 2048 / 4 + 255) / 256, 256, 0, stream>>>(h, hb, 4096 * 2048 / 4);
  split_wt1<<<(2048 * 768 + 255) / 256, 256, 0, stream>>>(Wt1, Wpre, Wab);
  biasprep<<<16, 256, 0, stream>>>(bih, bhh, bt1, biasp);

  // pre16 = f16(x @ [W_ih;W_t1x]^T + bias_pre)   (M=4096, N=4096, K=1024)
  {
    EpArgs e{};
    e.biasf = biasp;
    e.out_h = pre16;
    gemmT<0, 2, 2><<<dim3(16, 16), 512, 0, stream>>>(xb, Wpre, 4096, 1024, e);
  }

  const float dt = 1.0f / 3.0f;
  for (int s = 0; s < 3; ++s) {
    // k1 at h: EP1 then EP2 (h_mid = h + 0.5*dt*k1)
    {
      EpArgs e{};
      e.pre16 = pre16; e.h16 = hb; e.out_d = dif16; e.out_h = t1b;
      gemmT<1, 2, 2><<<dim3(16, 16), 512, 0, stream>>>(hb, Wab, 4096, 2048, e);
    }
    {
      EpArgs e{};
      e.bt2 = bt2; e.diff = dif16; e.hb16 = hb;
      e.coef = 0.5f * dt; e.out_f = nullptr; e.out_h = hmb;
      gemmT<2, 2, 1><<<dim3(16, 16), 512, 0, stream>>>(t1b, Wt2b, 2048, 2048, e);
    }
    // k2 at h_mid: EP1 then EP2 (h = h + dt*k2; in-place hb update is safe:
    // each idx is read then written by the same lane only)
    {
      EpArgs e{};
      e.pre16 = pre16; e.h16 = hmb; e.out_d = dif16; e.out_h = t1b;
      gemmT<1, 2, 2><<<dim3(16, 16), 512, 0, stream>>>(hmb, Wab, 4096, 2048, e);
    }
    {
      EpArgs e{};
      e.bt2 = bt2; e.diff = dif16; e.hb16 = hb;
      e.coef = dt; e.out_f = (s == 2) ? hout : nullptr; e.out_h = hb;
      gemmT<2, 2, 1><<<dim3(16, 16), 512, 0, stream>>>(t1b, Wt2b, 2048, 2048, e);
    }
  }
}